// Round 8
// baseline (1621.555 us; speedup 1.0000x reference)
//
#include <hip/hip_runtime.h>
#include <cstdint>
#include <cstddef>

#define BATCH 128
#define TLEN 4096
#define KS 64
#define NCHUNK 64  // chunk c covers t in [64c+1, min(64c+64, 4095)]

typedef __attribute__((ext_vector_type(4))) float f4;

__device__ __forceinline__ float f3(float a, float b, float c) {
  return fmaxf(fmaxf(a, b), c);  // folds to v_max3_f32
}

// max over m[64] without clobbering m. fp32 max returns an input bitwise,
// so any tree shape gives states bit-identical to the reference.
__device__ __forceinline__ float tree64(const float* m) {
  float t[22];
#pragma unroll
  for (int i = 0; i < 21; ++i) t[i] = f3(m[3 * i], m[3 * i + 1], m[3 * i + 2]);
  t[21] = m[63];
#pragma unroll
  for (int i = 0; i < 7; ++i) t[i] = f3(t[3 * i], t[3 * i + 1], t[3 * i + 2]);
  t[7] = t[21];
  t[0] = f3(t[0], t[1], t[2]);
  t[1] = f3(t[3], t[4], t[5]);
  t[2] = t[6];
  t[3] = t[7];
  t[0] = f3(t[0], t[1], t[2]);
  return fmaxf(t[0], t[3]);
}

// ===========================================================================
// R8: single-wave hand-asm forward chain with REGISTER-FILE broadcast.
//
// Ledger: R6 single-wave asm+LDS = 479 cyc/step (192 ds_read issue + 148
// VALU + ~100 LDS RAW + waits). R7 4-wave = 553 (barrier exchange > saved
// VALU — barrier-per-step is dead). R7 also validated v_readlane->SGPR->
// v_add_f32 as bit-exact and hazard-safe when batched.
//
// R8 = R6 structure, LDS broadcast replaced by 64 v_readlane with inline
// constant lanes (no memory, no lgkm, no RAW):
//   per step: 64 v_readlane (s36-s99) + 64 v_add_f32 (v96-159 = s+T with
//   T resident v32-95) + 32-op max3 tree -> v190 + emit add + 1 ring load.
//   ~164 instr ~ 330-400 cyc/step. Zero LDS in the loop.
// Emission ring: 4-deep, counted vmcnt(3), group-of-4 steps, base +1024 B
// per group, rewind on last group; checkpoint every 16 groups (CPBLK).
// 4095 steps = 3 HIP pre-steps + 1023 asm groups of 4.
// ===========================================================================

#define RL64 \
  "v_readlane_b32 s36, v176, 0\n"  "v_readlane_b32 s37, v176, 1\n" \
  "v_readlane_b32 s38, v176, 2\n"  "v_readlane_b32 s39, v176, 3\n" \
  "v_readlane_b32 s40, v176, 4\n"  "v_readlane_b32 s41, v176, 5\n" \
  "v_readlane_b32 s42, v176, 6\n"  "v_readlane_b32 s43, v176, 7\n" \
  "v_readlane_b32 s44, v176, 8\n"  "v_readlane_b32 s45, v176, 9\n" \
  "v_readlane_b32 s46, v176, 10\n" "v_readlane_b32 s47, v176, 11\n" \
  "v_readlane_b32 s48, v176, 12\n" "v_readlane_b32 s49, v176, 13\n" \
  "v_readlane_b32 s50, v176, 14\n" "v_readlane_b32 s51, v176, 15\n" \
  "v_readlane_b32 s52, v176, 16\n" "v_readlane_b32 s53, v176, 17\n" \
  "v_readlane_b32 s54, v176, 18\n" "v_readlane_b32 s55, v176, 19\n" \
  "v_readlane_b32 s56, v176, 20\n" "v_readlane_b32 s57, v176, 21\n" \
  "v_readlane_b32 s58, v176, 22\n" "v_readlane_b32 s59, v176, 23\n" \
  "v_readlane_b32 s60, v176, 24\n" "v_readlane_b32 s61, v176, 25\n" \
  "v_readlane_b32 s62, v176, 26\n" "v_readlane_b32 s63, v176, 27\n" \
  "v_readlane_b32 s64, v176, 28\n" "v_readlane_b32 s65, v176, 29\n" \
  "v_readlane_b32 s66, v176, 30\n" "v_readlane_b32 s67, v176, 31\n" \
  "v_readlane_b32 s68, v176, 32\n" "v_readlane_b32 s69, v176, 33\n" \
  "v_readlane_b32 s70, v176, 34\n" "v_readlane_b32 s71, v176, 35\n" \
  "v_readlane_b32 s72, v176, 36\n" "v_readlane_b32 s73, v176, 37\n" \
  "v_readlane_b32 s74, v176, 38\n" "v_readlane_b32 s75, v176, 39\n" \
  "v_readlane_b32 s76, v176, 40\n" "v_readlane_b32 s77, v176, 41\n" \
  "v_readlane_b32 s78, v176, 42\n" "v_readlane_b32 s79, v176, 43\n" \
  "v_readlane_b32 s80, v176, 44\n" "v_readlane_b32 s81, v176, 45\n" \
  "v_readlane_b32 s82, v176, 46\n" "v_readlane_b32 s83, v176, 47\n" \
  "v_readlane_b32 s84, v176, 48\n" "v_readlane_b32 s85, v176, 49\n" \
  "v_readlane_b32 s86, v176, 50\n" "v_readlane_b32 s87, v176, 51\n" \
  "v_readlane_b32 s88, v176, 52\n" "v_readlane_b32 s89, v176, 53\n" \
  "v_readlane_b32 s90, v176, 54\n" "v_readlane_b32 s91, v176, 55\n" \
  "v_readlane_b32 s92, v176, 56\n" "v_readlane_b32 s93, v176, 57\n" \
  "v_readlane_b32 s94, v176, 58\n" "v_readlane_b32 s95, v176, 59\n" \
  "v_readlane_b32 s96, v176, 60\n" "v_readlane_b32 s97, v176, 61\n" \
  "v_readlane_b32 s98, v176, 62\n" "v_readlane_b32 s99, v176, 63\n"

#define ADD64 \
  "v_add_f32 v96, s36, v32\n"   "v_add_f32 v97, s37, v33\n" \
  "v_add_f32 v98, s38, v34\n"   "v_add_f32 v99, s39, v35\n" \
  "v_add_f32 v100, s40, v36\n"  "v_add_f32 v101, s41, v37\n" \
  "v_add_f32 v102, s42, v38\n"  "v_add_f32 v103, s43, v39\n" \
  "v_add_f32 v104, s44, v40\n"  "v_add_f32 v105, s45, v41\n" \
  "v_add_f32 v106, s46, v42\n"  "v_add_f32 v107, s47, v43\n" \
  "v_add_f32 v108, s48, v44\n"  "v_add_f32 v109, s49, v45\n" \
  "v_add_f32 v110, s50, v46\n"  "v_add_f32 v111, s51, v47\n" \
  "v_add_f32 v112, s52, v48\n"  "v_add_f32 v113, s53, v49\n" \
  "v_add_f32 v114, s54, v50\n"  "v_add_f32 v115, s55, v51\n" \
  "v_add_f32 v116, s56, v52\n"  "v_add_f32 v117, s57, v53\n" \
  "v_add_f32 v118, s58, v54\n"  "v_add_f32 v119, s59, v55\n" \
  "v_add_f32 v120, s60, v56\n"  "v_add_f32 v121, s61, v57\n" \
  "v_add_f32 v122, s62, v58\n"  "v_add_f32 v123, s63, v59\n" \
  "v_add_f32 v124, s64, v60\n"  "v_add_f32 v125, s65, v61\n" \
  "v_add_f32 v126, s66, v62\n"  "v_add_f32 v127, s67, v63\n" \
  "v_add_f32 v128, s68, v64\n"  "v_add_f32 v129, s69, v65\n" \
  "v_add_f32 v130, s70, v66\n"  "v_add_f32 v131, s71, v67\n" \
  "v_add_f32 v132, s72, v68\n"  "v_add_f32 v133, s73, v69\n" \
  "v_add_f32 v134, s74, v70\n"  "v_add_f32 v135, s75, v71\n" \
  "v_add_f32 v136, s76, v72\n"  "v_add_f32 v137, s77, v73\n" \
  "v_add_f32 v138, s78, v74\n"  "v_add_f32 v139, s79, v75\n" \
  "v_add_f32 v140, s80, v76\n"  "v_add_f32 v141, s81, v77\n" \
  "v_add_f32 v142, s82, v78\n"  "v_add_f32 v143, s83, v79\n" \
  "v_add_f32 v144, s84, v80\n"  "v_add_f32 v145, s85, v81\n" \
  "v_add_f32 v146, s86, v82\n"  "v_add_f32 v147, s87, v83\n" \
  "v_add_f32 v148, s88, v84\n"  "v_add_f32 v149, s89, v85\n" \
  "v_add_f32 v150, s90, v86\n"  "v_add_f32 v151, s91, v87\n" \
  "v_add_f32 v152, s92, v88\n"  "v_add_f32 v153, s93, v89\n" \
  "v_add_f32 v154, s94, v90\n"  "v_add_f32 v155, s95, v91\n" \
  "v_add_f32 v156, s96, v92\n"  "v_add_f32 v157, s97, v93\n" \
  "v_add_f32 v158, s98, v94\n"  "v_add_f32 v159, s99, v95\n"

// 64 -> 1 max via v_max3 tree (21 + 7 + 2 + 1 + 1 = 32 ops), result v190.
// In-place dests v(96+i) never clobber a not-yet-read source (dest index
// 96+i, sources start at 96+3i; its own consumer ran at iter floor(i/3)<i).
#define TREE64A \
  "v_max3_f32 v96, v96, v97, v98\n" \
  "v_max3_f32 v97, v99, v100, v101\n" \
  "v_max3_f32 v98, v102, v103, v104\n" \
  "v_max3_f32 v99, v105, v106, v107\n" \
  "v_max3_f32 v100, v108, v109, v110\n" \
  "v_max3_f32 v101, v111, v112, v113\n" \
  "v_max3_f32 v102, v114, v115, v116\n" \
  "v_max3_f32 v103, v117, v118, v119\n" \
  "v_max3_f32 v104, v120, v121, v122\n" \
  "v_max3_f32 v105, v123, v124, v125\n" \
  "v_max3_f32 v106, v126, v127, v128\n" \
  "v_max3_f32 v107, v129, v130, v131\n" \
  "v_max3_f32 v108, v132, v133, v134\n" \
  "v_max3_f32 v109, v135, v136, v137\n" \
  "v_max3_f32 v110, v138, v139, v140\n" \
  "v_max3_f32 v111, v141, v142, v143\n" \
  "v_max3_f32 v112, v144, v145, v146\n" \
  "v_max3_f32 v113, v147, v148, v149\n" \
  "v_max3_f32 v114, v150, v151, v152\n" \
  "v_max3_f32 v115, v153, v154, v155\n" \
  "v_max3_f32 v116, v156, v157, v158\n" \
  "v_max3_f32 v96, v96, v97, v98\n" \
  "v_max3_f32 v97, v99, v100, v101\n" \
  "v_max3_f32 v98, v102, v103, v104\n" \
  "v_max3_f32 v99, v105, v106, v107\n" \
  "v_max3_f32 v100, v108, v109, v110\n" \
  "v_max3_f32 v101, v111, v112, v113\n" \
  "v_max3_f32 v102, v114, v115, v116\n" \
  "v_max3_f32 v160, v96, v97, v98\n" \
  "v_max3_f32 v161, v99, v100, v101\n" \
  "v_max3_f32 v160, v160, v161, v102\n" \
  "v_max_f32 v190, v160, v159\n"

// one time-step: readlane broadcast, add T, reduce, add emission EK,
// optional checkpoint EXTRA, issue next emission load at LDOFF
#define POS(EK, LDOFF, EXTRA) \
  RL64 \
  ADD64 \
  TREE64A \
  "s_waitcnt vmcnt(3)\n" \
  "v_add_f32 v176, v190, " EK "\n" \
  EXTRA \
  "global_load_dword " EK ", v[192:193], off offset:" LDOFF "\n"

// checkpoint: every 16th group (s20&15==0) at POS1 -> t = 64,128,...,4032
#define CPBLK \
  "s_and_b32 s21, s20, 15\n" \
  "s_cmp_eq_u32 s21, 0\n" \
  "s_cbranch_scc0 NOCP%=\n" \
  "global_store_dword v[194:195], v176, off\n" \
  "v_add_co_u32 v194, vcc, 0x100, v194\n" \
  "v_addc_co_u32 v195, vcc, 0, v195, vcc\n" \
  "s_waitcnt vmcnt(0)\n" \
  "NOCP%=:\n"

__global__ __launch_bounds__(64, 1) void crf_fwd(
    const float* __restrict__ pot, const float* __restrict__ trans,
    float* __restrict__ cp, float* __restrict__ fin) {
  const int b = blockIdx.x;
  const int j = threadIdx.x;
  __shared__ float smf[KS];  // pre-step broadcast only (256 B)

  const float* pb = pot + (size_t)b * TLEN * KS + j;
  float* cpb = cp + (size_t)b * NCHUNK * KS + j;

  float s = pb[0];
  cpb[0] = s;
  smf[j] = s;

  // 3 HIP pre-steps (t=1..3); 4095 = 3 + 4*1023. Single wave: in-order LDS.
  for (int t = 1; t <= 3; ++t) {
    float p[16];
#pragma unroll
    for (int q = 0; q < 16; ++q) {
      float a0 = smf[4 * q + 0] + trans[(4 * q + 0) * KS + j];
      float a1 = smf[4 * q + 1] + trans[(4 * q + 1) * KS + j];
      float a2 = smf[4 * q + 2] + trans[(4 * q + 2) * KS + j];
      float a3 = smf[4 * q + 3] + trans[(4 * q + 3) * KS + j];
      p[q] = fmaxf(f3(a0, a1, a2), a3);
    }
    float u0 = f3(p[0], p[1], p[2]);
    float u1 = f3(p[3], p[4], p[5]);
    float u2 = f3(p[6], p[7], p[8]);
    float u3 = f3(p[9], p[10], p[11]);
    float u4 = f3(p[12], p[13], p[14]);
    s = fmaxf(f3(u0, u1, u2), f3(u3, u4, p[15])) + pb[(size_t)t * KS];
    smf[j] = s;
  }

  uint64_t tca = (uint64_t)(uintptr_t)(trans + j);           // T col base
  uint64_t em = (uint64_t)(uintptr_t)(pb + (size_t)4 * KS);  // row t=4
  uint64_t cpa = (uint64_t)(uintptr_t)(cpb + KS);            // cp row 1
  uint64_t fa = (uint64_t)(uintptr_t)(fin + (size_t)b * KS + j);

  asm volatile(
      // ---- prologue ----
      "s_waitcnt vmcnt(0) lgkmcnt(0)\n"
      "v_mov_b32 v176, %[sinit]\n"
      // T column -> v32..v95 (16 loads per 4096-B base window; global_load
      // imm offset is 13-bit signed, so advance the base every 16 rows)
      "v_mov_b32 v192, %[tclo]\n"
      "v_mov_b32 v193, %[tchi]\n"
      "global_load_dword v32, v[192:193], off offset:0\n"
      "global_load_dword v33, v[192:193], off offset:256\n"
      "global_load_dword v34, v[192:193], off offset:512\n"
      "global_load_dword v35, v[192:193], off offset:768\n"
      "global_load_dword v36, v[192:193], off offset:1024\n"
      "global_load_dword v37, v[192:193], off offset:1280\n"
      "global_load_dword v38, v[192:193], off offset:1536\n"
      "global_load_dword v39, v[192:193], off offset:1792\n"
      "global_load_dword v40, v[192:193], off offset:2048\n"
      "global_load_dword v41, v[192:193], off offset:2304\n"
      "global_load_dword v42, v[192:193], off offset:2560\n"
      "global_load_dword v43, v[192:193], off offset:2816\n"
      "global_load_dword v44, v[192:193], off offset:3072\n"
      "global_load_dword v45, v[192:193], off offset:3328\n"
      "global_load_dword v46, v[192:193], off offset:3584\n"
      "global_load_dword v47, v[192:193], off offset:3840\n"
      "v_add_co_u32 v192, vcc, 0x1000, v192\n"
      "v_addc_co_u32 v193, vcc, 0, v193, vcc\n"
      "global_load_dword v48, v[192:193], off offset:0\n"
      "global_load_dword v49, v[192:193], off offset:256\n"
      "global_load_dword v50, v[192:193], off offset:512\n"
      "global_load_dword v51, v[192:193], off offset:768\n"
      "global_load_dword v52, v[192:193], off offset:1024\n"
      "global_load_dword v53, v[192:193], off offset:1280\n"
      "global_load_dword v54, v[192:193], off offset:1536\n"
      "global_load_dword v55, v[192:193], off offset:1792\n"
      "global_load_dword v56, v[192:193], off offset:2048\n"
      "global_load_dword v57, v[192:193], off offset:2304\n"
      "global_load_dword v58, v[192:193], off offset:2560\n"
      "global_load_dword v59, v[192:193], off offset:2816\n"
      "global_load_dword v60, v[192:193], off offset:3072\n"
      "global_load_dword v61, v[192:193], off offset:3328\n"
      "global_load_dword v62, v[192:193], off offset:3584\n"
      "global_load_dword v63, v[192:193], off offset:3840\n"
      "v_add_co_u32 v192, vcc, 0x1000, v192\n"
      "v_addc_co_u32 v193, vcc, 0, v193, vcc\n"
      "global_load_dword v64, v[192:193], off offset:0\n"
      "global_load_dword v65, v[192:193], off offset:256\n"
      "global_load_dword v66, v[192:193], off offset:512\n"
      "global_load_dword v67, v[192:193], off offset:768\n"
      "global_load_dword v68, v[192:193], off offset:1024\n"
      "global_load_dword v69, v[192:193], off offset:1280\n"
      "global_load_dword v70, v[192:193], off offset:1536\n"
      "global_load_dword v71, v[192:193], off offset:1792\n"
      "global_load_dword v72, v[192:193], off offset:2048\n"
      "global_load_dword v73, v[192:193], off offset:2304\n"
      "global_load_dword v74, v[192:193], off offset:2560\n"
      "global_load_dword v75, v[192:193], off offset:2816\n"
      "global_load_dword v76, v[192:193], off offset:3072\n"
      "global_load_dword v77, v[192:193], off offset:3328\n"
      "global_load_dword v78, v[192:193], off offset:3584\n"
      "global_load_dword v79, v[192:193], off offset:3840\n"
      "v_add_co_u32 v192, vcc, 0x1000, v192\n"
      "v_addc_co_u32 v193, vcc, 0, v193, vcc\n"
      "global_load_dword v80, v[192:193], off offset:0\n"
      "global_load_dword v81, v[192:193], off offset:256\n"
      "global_load_dword v82, v[192:193], off offset:512\n"
      "global_load_dword v83, v[192:193], off offset:768\n"
      "global_load_dword v84, v[192:193], off offset:1024\n"
      "global_load_dword v85, v[192:193], off offset:1280\n"
      "global_load_dword v86, v[192:193], off offset:1536\n"
      "global_load_dword v87, v[192:193], off offset:1792\n"
      "global_load_dword v88, v[192:193], off offset:2048\n"
      "global_load_dword v89, v[192:193], off offset:2304\n"
      "global_load_dword v90, v[192:193], off offset:2560\n"
      "global_load_dword v91, v[192:193], off offset:2816\n"
      "global_load_dword v92, v[192:193], off offset:3072\n"
      "global_load_dword v93, v[192:193], off offset:3328\n"
      "global_load_dword v94, v[192:193], off offset:3584\n"
      "global_load_dword v95, v[192:193], off offset:3840\n"
      // emission ring: rows t=4..7
      "v_mov_b32 v192, %[emlo]\n"
      "v_mov_b32 v193, %[emhi]\n"
      "global_load_dword v177, v[192:193], off offset:0\n"
      "global_load_dword v178, v[192:193], off offset:256\n"
      "global_load_dword v179, v[192:193], off offset:512\n"
      "global_load_dword v180, v[192:193], off offset:768\n"
      "v_mov_b32 v194, %[cplo]\n"
      "v_mov_b32 v195, %[cphi]\n"
      "v_mov_b32 v196, %[fnlo]\n"
      "v_mov_b32 v197, %[fnhi]\n"
      // T loads done (4 ring loads may stay outstanding)
      "s_waitcnt vmcnt(4)\n"
      "s_mov_b32 s20, 1023\n"
      // ---- main loop: 1023 groups x 4 steps ----
      "CRFLOOP%=:\n"
      // last group: rewind emis base 4096 B so prefetches stay in-bounds
      "s_cmp_eq_u32 s20, 1\n"
      "s_cbranch_scc0 NOADJ%=\n"
      "v_add_co_u32 v192, vcc, 0xfffff000, v192\n"
      "v_addc_co_u32 v193, vcc, -1, v193, vcc\n"
      "NOADJ%=:\n"
      POS("v177", "1024", CPBLK)
      POS("v178", "1280", "")
      POS("v179", "1536", "")
      POS("v180", "1792", "")
      // advance emission base one group (4 rows = 1024 B)
      "v_add_co_u32 v192, vcc, 0x400, v192\n"
      "v_addc_co_u32 v193, vcc, 0, v193, vcc\n"
      "s_sub_u32 s20, s20, 1\n"
      "s_cmp_lg_u32 s20, 0\n"
      "s_cbranch_scc1 CRFLOOP%=\n"
      // ---- epilogue: final state ----
      "global_store_dword v[196:197], v176, off\n"
      "s_waitcnt vmcnt(0)\n"
      :
      : [sinit] "v"(s),
        [tclo] "v"((uint32_t)tca), [tchi] "v"((uint32_t)(tca >> 32)),
        [emlo] "v"((uint32_t)em), [emhi] "v"((uint32_t)(em >> 32)),
        [cplo] "v"((uint32_t)cpa), [cphi] "v"((uint32_t)(cpa >> 32)),
        [fnlo] "v"((uint32_t)fa), [fnhi] "v"((uint32_t)(fa >> 32))
      : "memory", "vcc", "scc", "s20", "s21",
        "s36", "s37", "s38", "s39", "s40", "s41", "s42", "s43", "s44", "s45",
        "s46", "s47", "s48", "s49", "s50", "s51", "s52", "s53", "s54", "s55",
        "s56", "s57", "s58", "s59", "s60", "s61", "s62", "s63", "s64", "s65",
        "s66", "s67", "s68", "s69", "s70", "s71", "s72", "s73", "s74", "s75",
        "s76", "s77", "s78", "s79", "s80", "s81", "s82", "s83", "s84", "s85",
        "s86", "s87", "s88", "s89", "s90", "s91", "s92", "s93", "s94", "s95",
        "s96", "s97", "s98", "s99",
        "v32", "v33", "v34", "v35", "v36", "v37", "v38", "v39", "v40", "v41",
        "v42", "v43", "v44", "v45", "v46", "v47", "v48", "v49", "v50", "v51",
        "v52", "v53", "v54", "v55", "v56", "v57", "v58", "v59", "v60", "v61",
        "v62", "v63", "v64", "v65", "v66", "v67", "v68", "v69", "v70", "v71",
        "v72", "v73", "v74", "v75", "v76", "v77", "v78", "v79", "v80", "v81",
        "v82", "v83", "v84", "v85", "v86", "v87", "v88", "v89", "v90", "v91",
        "v92", "v93", "v94", "v95", "v96", "v97", "v98", "v99", "v100",
        "v101", "v102", "v103", "v104", "v105", "v106", "v107", "v108",
        "v109", "v110", "v111", "v112", "v113", "v114", "v115", "v116",
        "v117", "v118", "v119", "v120", "v121", "v122", "v123", "v124",
        "v125", "v126", "v127", "v128", "v129", "v130", "v131", "v132",
        "v133", "v134", "v135", "v136", "v137", "v138", "v139", "v140",
        "v141", "v142", "v143", "v144", "v145", "v146", "v147", "v148",
        "v149", "v150", "v151", "v152", "v153", "v154", "v155", "v156",
        "v157", "v158", "v159", "v160", "v161", "v176", "v177", "v178",
        "v179", "v180", "v190", "v192", "v193", "v194", "v195", "v196",
        "v197");
}

// ---------------------------------------------------------------------------
// Backpointer reconstruction (unchanged, best-measured rest-of-pipeline):
// per (batch, chunk) wave recomputes states from the checkpoint
// (bit-identical: fp32 max is exact, sums identical), derives bp[t][j],
// and fuses the speculative chunk-map chase via ds_bpermute.
// 8192 waves -> latency hidden by TLP.
// ---------------------------------------------------------------------------
__global__ __launch_bounds__(64) void crf_bp(
    const float* __restrict__ pot, const float* __restrict__ trans,
    const float* __restrict__ cp, unsigned char* __restrict__ bp,
    unsigned char* __restrict__ map) {
  const int b = blockIdx.x;
  const int ch = blockIdx.y;
  const int j = threadIdx.x;
  __shared__ float4 sm4[KS / 4];
  float* sm = (float*)sm4;

  float c[KS];
#pragma unroll
  for (int i = 0; i < KS; ++i) c[i] = trans[i * KS + j];

  float s = cp[((size_t)b * NCHUNK + ch) * KS + j];
  const int t0 = ch * 64;
  const int hi = min(t0 + 64, TLEN - 1);
  const float* pb = pot + (size_t)b * TLEN * KS + j;
  unsigned char* bpb = bp + (size_t)b * TLEN * KS + j;

  sm[j] = s;
  int tag = j;  // forward-composed backward map
  float emit = pb[(size_t)(t0 + 1) * KS];
  for (int t = t0 + 1; t <= hi; ++t) {
    float emit_next = pb[(size_t)min(t + 1, TLEN - 1) * KS];

    float m[KS];
#pragma unroll
    for (int q = 0; q < KS / 4; ++q) {
      float4 v = sm4[q];
      m[4 * q + 0] = v.x + c[4 * q + 0];
      m[4 * q + 1] = v.y + c[4 * q + 1];
      m[4 * q + 2] = v.z + c[4 * q + 2];
      m[4 * q + 3] = v.w + c[4 * q + 3];
    }
    float best = tree64(m);

    // first-occurrence argmax: descending exact-equality scan
    int bi = 63;
#pragma unroll
    for (int i = 62; i >= 0; --i) bi = (m[i] == best) ? i : bi;

    bpb[(size_t)t * KS] = (unsigned char)bi;
    s = best + emit;
    sm[j] = s;
    emit = emit_next;

    // g_t[k] = g_{t-1}[bp_t[k]]: lane k pulls lane bi_k's tag
    tag = __builtin_amdgcn_ds_bpermute(bi << 2, tag);
  }
  map[((size_t)b * NCHUNK + ch) * KS + j] = (unsigned char)tag;
}

// ---------------------------------------------------------------------------
// Compose chunk maps per batch (serial over 64 chunks, parallel over batches).
// Also does the final-state argmax (first-occurrence, strict >).
// ---------------------------------------------------------------------------
__global__ void crf_compose(const unsigned char* __restrict__ map,
                            const float* __restrict__ fin,
                            unsigned char* __restrict__ e,
                            int* __restrict__ tags_out) {
  const int b = blockIdx.x * blockDim.x + threadIdx.x;
  if (b >= BATCH) return;
  const float* fb = fin + (size_t)b * KS;
  float best = fb[0];
  int cur = 0;
  for (int i = 1; i < KS; ++i) {
    float v = fb[i];
    if (v > best) { best = v; cur = i; }
  }
  tags_out[(size_t)b * TLEN + (TLEN - 1)] = cur;
  for (int ch = NCHUNK - 1; ch >= 0; --ch) {
    e[(size_t)b * NCHUNK + ch] = (unsigned char)cur;
    cur = map[((size_t)b * NCHUNK + ch) * KS + cur];
  }
}

// ---------------------------------------------------------------------------
// Extract per-chunk paths from known entering tags (parallel over B*NCHUNK).
// ---------------------------------------------------------------------------
__global__ void crf_extract(const unsigned char* __restrict__ bp,
                            const unsigned char* __restrict__ e,
                            int* __restrict__ tags_out) {
  const int idx = blockIdx.x * blockDim.x + threadIdx.x;  // b*NCHUNK + c
  if (idx >= BATCH * NCHUNK) return;
  const int b = idx >> 6;
  const int c = idx & (NCHUNK - 1);
  const int lo = 64 * c + 1;
  const int hi = min(64 * c + 64, TLEN - 1);
  const unsigned char* bpb = bp + (size_t)b * TLEN * KS;
  int* to = tags_out + (size_t)b * TLEN;
  int tag = e[(size_t)b * NCHUNK + c];
  for (int t = hi; t >= lo; --t) {
    tag = bpb[(size_t)t * KS + tag];
    to[t - 1] = tag;
  }
}

// ---------------------------------------------------------------------------
// Sequence lengths = sum(mask) per batch.
// ---------------------------------------------------------------------------
__global__ __launch_bounds__(64) void crf_lens(const int* __restrict__ mask,
                                               int* __restrict__ out) {
  const int b = blockIdx.x;
  const int l = threadIdx.x;
  const int* mb = mask + (size_t)b * TLEN;
  int sum = 0;
  for (int t = l; t < TLEN; t += 64) sum += mb[t];
#pragma unroll
  for (int off = 32; off > 0; off >>= 1) sum += __shfl_down(sum, off, 64);
  if (l == 0) out[b] = sum;
}

extern "C" void kernel_launch(void* const* d_in, const int* in_sizes, int n_in,
                              void* d_out, int out_size, void* d_ws,
                              size_t ws_size, hipStream_t stream) {
  const float* pot = (const float*)d_in[0];    // (128, 4096, 64) fp32
  const float* trans = (const float*)d_in[1];  // (64, 64) fp32
  const int* mask = (const int*)d_in[2];       // (128, 4096) int32

  int* out = (int*)d_out;  // [tags: 128*4096][lens: 128]
  int* tags_out = out;
  int* lens_out = out + (size_t)BATCH * TLEN;

  // workspace layout
  char* w = (char*)d_ws;
  unsigned char* bp = (unsigned char*)w;                     // 33,554,432 B
  float* cp = (float*)(bp + (size_t)BATCH * TLEN * KS);      //  2,097,152 B
  float* fin = cp + (size_t)BATCH * NCHUNK * KS;             //     32,768 B
  unsigned char* map = (unsigned char*)(fin + (size_t)BATCH * KS);  // 524,288 B
  unsigned char* e = map + (size_t)BATCH * NCHUNK * KS;      //      8,192 B

  crf_fwd<<<BATCH, 64, 0, stream>>>(pot, trans, cp, fin);
  crf_lens<<<BATCH, 64, 0, stream>>>(mask, lens_out);
  crf_bp<<<dim3(BATCH, NCHUNK), 64, 0, stream>>>(pot, trans, cp, bp, map);
  crf_compose<<<1, BATCH, 0, stream>>>(map, fin, e, tags_out);
  crf_extract<<<(BATCH * NCHUNK + 255) / 256, 256, 0, stream>>>(bp, e, tags_out);
}

// Round 9
// 1150.368 us; speedup vs baseline: 1.4096x; 1.4096x over previous
//
#include <hip/hip_runtime.h>
#include <cstdint>
#include <cstddef>

#define BATCH 128
#define TLEN 4096
#define KS 64
#define NCHUNK 64  // chunk c covers t in [64c+1, min(64c+64, 4095)]

typedef __attribute__((ext_vector_type(4))) float f4;

__device__ __forceinline__ float f3(float a, float b, float c) {
  return fmaxf(fmaxf(a, b), c);  // folds to v_max3_f32
}

// max over m[64] without clobbering m. fp32 max returns an input bitwise,
// so any tree shape gives states bit-identical to the reference.
__device__ __forceinline__ float tree64(const float* m) {
  float t[22];
#pragma unroll
  for (int i = 0; i < 21; ++i) t[i] = f3(m[3 * i], m[3 * i + 1], m[3 * i + 2]);
  t[21] = m[63];
#pragma unroll
  for (int i = 0; i < 7; ++i) t[i] = f3(t[3 * i], t[3 * i + 1], t[3 * i + 2]);
  t[7] = t[21];
  t[0] = f3(t[0], t[1], t[2]);
  t[1] = f3(t[3], t[4], t[5]);
  t[2] = t[6];
  t[3] = t[7];
  t[0] = f3(t[0], t[1], t[2]);
  return fmaxf(t[0], t[3]);
}

// ===========================================================================
// R9 = R6 (the 479 cyc/step champion) with ONE change: 4-stage fine-grained
// lgkmcnt pipelining. R6's 2-stage wait (lgkm(8) -> 32 VALU -> lgkm(0))
// exposed ~100 cyc of LDS return latency. The DS pipe is in-order per wave,
// so lgkmcnt(N) maps exactly to "oldest 17-N of {write,read0..15} retired":
//   lgkm(12) -> write+reads 0-3 home  -> quads 0-3
//   lgkm(8)  -> reads 4-7 home        -> quads 4-7
//   lgkm(4)  -> reads 8-11 home       -> quads 8-11
//   lgkm(0)  -> all home              -> quads 12-15 + tree
// Broadcast-mechanism ledger (cyc/step): R6 asm+LDS 479 | R7 4-wave 553 |
// R8 readlane 727 | compiler-scheduled 830-1000. LDS + hand schedule wins;
// this round reclaims the remaining exposed latency inside that structure.
// Register map: v32-95 T, v96-159 state, v160-175 partials, v176 s,
// v177-180 e-ring, v183 wa, v184 ta, v189 za, v190 temp, v192:193 emis,
// v194:195 cp, v196:197 fin; s20 ctr, s21 tmp.
// 4095 steps = 3 HIP pre-steps + 1023 asm groups of 4.
// ===========================================================================

#define RD16 \
  "ds_read_b128 v[96:99], v189 offset:0\n"    \
  "ds_read_b128 v[100:103], v189 offset:16\n" \
  "ds_read_b128 v[104:107], v189 offset:32\n" \
  "ds_read_b128 v[108:111], v189 offset:48\n" \
  "ds_read_b128 v[112:115], v189 offset:64\n" \
  "ds_read_b128 v[116:119], v189 offset:80\n" \
  "ds_read_b128 v[120:123], v189 offset:96\n" \
  "ds_read_b128 v[124:127], v189 offset:112\n" \
  "ds_read_b128 v[128:131], v189 offset:128\n" \
  "ds_read_b128 v[132:135], v189 offset:144\n" \
  "ds_read_b128 v[136:139], v189 offset:160\n" \
  "ds_read_b128 v[140:143], v189 offset:176\n" \
  "ds_read_b128 v[144:147], v189 offset:192\n" \
  "ds_read_b128 v[148:151], v189 offset:208\n" \
  "ds_read_b128 v[152:155], v189 offset:224\n" \
  "ds_read_b128 v[156:159], v189 offset:240\n"

#define QUADS03 \
  "v_pk_add_f32 v[96:97], v[96:97], v[32:33]\n"    \
  "v_pk_add_f32 v[98:99], v[98:99], v[34:35]\n"    \
  "v_max3_f32 v160, v96, v97, v98\n"               \
  "v_max_f32 v160, v160, v99\n"                    \
  "v_pk_add_f32 v[100:101], v[100:101], v[36:37]\n" \
  "v_pk_add_f32 v[102:103], v[102:103], v[38:39]\n" \
  "v_max3_f32 v161, v100, v101, v102\n"            \
  "v_max_f32 v161, v161, v103\n"                   \
  "v_pk_add_f32 v[104:105], v[104:105], v[40:41]\n" \
  "v_pk_add_f32 v[106:107], v[106:107], v[42:43]\n" \
  "v_max3_f32 v162, v104, v105, v106\n"            \
  "v_max_f32 v162, v162, v107\n"                   \
  "v_pk_add_f32 v[108:109], v[108:109], v[44:45]\n" \
  "v_pk_add_f32 v[110:111], v[110:111], v[46:47]\n" \
  "v_max3_f32 v163, v108, v109, v110\n"            \
  "v_max_f32 v163, v163, v111\n"

#define QUADS47 \
  "v_pk_add_f32 v[112:113], v[112:113], v[48:49]\n" \
  "v_pk_add_f32 v[114:115], v[114:115], v[50:51]\n" \
  "v_max3_f32 v164, v112, v113, v114\n"            \
  "v_max_f32 v164, v164, v115\n"                   \
  "v_pk_add_f32 v[116:117], v[116:117], v[52:53]\n" \
  "v_pk_add_f32 v[118:119], v[118:119], v[54:55]\n" \
  "v_max3_f32 v165, v116, v117, v118\n"            \
  "v_max_f32 v165, v165, v119\n"                   \
  "v_pk_add_f32 v[120:121], v[120:121], v[56:57]\n" \
  "v_pk_add_f32 v[122:123], v[122:123], v[58:59]\n" \
  "v_max3_f32 v166, v120, v121, v122\n"            \
  "v_max_f32 v166, v166, v123\n"                   \
  "v_pk_add_f32 v[124:125], v[124:125], v[60:61]\n" \
  "v_pk_add_f32 v[126:127], v[126:127], v[62:63]\n" \
  "v_max3_f32 v167, v124, v125, v126\n"            \
  "v_max_f32 v167, v167, v127\n"

#define QUADS811 \
  "v_pk_add_f32 v[128:129], v[128:129], v[64:65]\n" \
  "v_pk_add_f32 v[130:131], v[130:131], v[66:67]\n" \
  "v_max3_f32 v168, v128, v129, v130\n"            \
  "v_max_f32 v168, v168, v131\n"                   \
  "v_pk_add_f32 v[132:133], v[132:133], v[68:69]\n" \
  "v_pk_add_f32 v[134:135], v[134:135], v[70:71]\n" \
  "v_max3_f32 v169, v132, v133, v134\n"            \
  "v_max_f32 v169, v169, v135\n"                   \
  "v_pk_add_f32 v[136:137], v[136:137], v[72:73]\n" \
  "v_pk_add_f32 v[138:139], v[138:139], v[74:75]\n" \
  "v_max3_f32 v170, v136, v137, v138\n"            \
  "v_max_f32 v170, v170, v139\n"                   \
  "v_pk_add_f32 v[140:141], v[140:141], v[76:77]\n" \
  "v_pk_add_f32 v[142:143], v[142:143], v[78:79]\n" \
  "v_max3_f32 v171, v140, v141, v142\n"            \
  "v_max_f32 v171, v171, v143\n"

#define QUADS1215 \
  "v_pk_add_f32 v[144:145], v[144:145], v[80:81]\n" \
  "v_pk_add_f32 v[146:147], v[146:147], v[82:83]\n" \
  "v_max3_f32 v172, v144, v145, v146\n"            \
  "v_max_f32 v172, v172, v147\n"                   \
  "v_pk_add_f32 v[148:149], v[148:149], v[84:85]\n" \
  "v_pk_add_f32 v[150:151], v[150:151], v[86:87]\n" \
  "v_max3_f32 v173, v148, v149, v150\n"            \
  "v_max_f32 v173, v173, v151\n"                   \
  "v_pk_add_f32 v[152:153], v[152:153], v[88:89]\n" \
  "v_pk_add_f32 v[154:155], v[154:155], v[90:91]\n" \
  "v_max3_f32 v174, v152, v153, v154\n"            \
  "v_max_f32 v174, v174, v155\n"                   \
  "v_pk_add_f32 v[156:157], v[156:157], v[92:93]\n" \
  "v_pk_add_f32 v[158:159], v[158:159], v[94:95]\n" \
  "v_max3_f32 v175, v156, v157, v158\n"            \
  "v_max_f32 v175, v175, v159\n"

#define TREE16 \
  "v_max3_f32 v190, v160, v161, v162\n" \
  "v_max3_f32 v191, v163, v164, v165\n" \
  "v_max3_f32 v160, v166, v167, v168\n" \
  "v_max3_f32 v161, v169, v170, v171\n" \
  "v_max3_f32 v162, v172, v173, v174\n" \
  "v_max3_f32 v163, v190, v191, v160\n" \
  "v_max3_f32 v164, v161, v162, v175\n" \
  "v_max_f32 v190, v163, v164\n"

// one time-step: 16 reads issued back-to-back, then 4-stage counted waits
// releasing quads as their data retires (in-order DS pipe; the previous
// step's ds_write is the oldest op and is counted first).
#define POS(EK, LDOFF, EXTRA) \
  RD16 \
  "s_waitcnt lgkmcnt(12)\n" \
  QUADS03 \
  "s_waitcnt lgkmcnt(8)\n" \
  QUADS47 \
  "s_waitcnt lgkmcnt(4)\n" \
  QUADS811 \
  "s_waitcnt lgkmcnt(0)\n" \
  QUADS1215 \
  TREE16 \
  "s_waitcnt vmcnt(3)\n" \
  "v_add_f32 v176, v190, " EK "\n" \
  "ds_write_b32 v183, v176\n" \
  EXTRA \
  "global_load_dword " EK ", v[192:193], off offset:" LDOFF "\n"

#define CPBLK \
  "s_and_b32 s21, s20, 15\n" \
  "s_cmp_eq_u32 s21, 0\n" \
  "s_cbranch_scc0 NOCP%=\n" \
  "global_store_dword v[194:195], v176, off\n" \
  "v_add_co_u32 v194, vcc, 0x100, v194\n" \
  "v_addc_co_u32 v195, vcc, 0, v195, vcc\n" \
  "s_waitcnt vmcnt(0)\n" \
  "NOCP%=:\n"

__global__ __launch_bounds__(64, 1) void crf_fwd(
    const float* __restrict__ pot, const float* __restrict__ trans,
    float* __restrict__ cp, float* __restrict__ fin) {
  const int b = blockIdx.x;
  const int j = threadIdx.x;
  __shared__ f4 sm4[KS / 4];         // state broadcast (256 B)
  __shared__ f4 tl4[(KS / 4) * KS];  // transition tile (16 KB)
  float* sm = (float*)sm4;

  // stage transition tile: lane j fills its own column (coalesced loads)
#pragma unroll
  for (int q = 0; q < KS / 4; ++q) {
    f4 v;
    v.x = trans[(4 * q + 0) * KS + j];
    v.y = trans[(4 * q + 1) * KS + j];
    v.z = trans[(4 * q + 2) * KS + j];
    v.w = trans[(4 * q + 3) * KS + j];
    tl4[q * KS + j] = v;
  }
  // single wave -> in-order LDS; no barrier needed anywhere

  const float* pb = pot + (size_t)b * TLEN * KS + j;
  float* cpb = cp + (size_t)b * NCHUNK * KS + j;

  float s = pb[0];
  cpb[0] = s;
  sm[j] = s;

  // 3 HIP pre-steps (t=1..3); 4095 = 3 + 4*1023
  for (int t = 1; t <= 3; ++t) {
    float emit = pb[(size_t)t * KS];
    float p[KS / 4];
#pragma unroll
    for (int q = 0; q < KS / 4; ++q) {
      f4 v = sm4[q];
      f4 c = tl4[q * KS + j];
      float a0 = v.x + c.x, a1 = v.y + c.y, a2 = v.z + c.z, a3 = v.w + c.w;
      p[q] = fmaxf(f3(a0, a1, a2), a3);
    }
    float u0 = f3(p[0], p[1], p[2]);
    float u1 = f3(p[3], p[4], p[5]);
    float u2 = f3(p[6], p[7], p[8]);
    float u3 = f3(p[9], p[10], p[11]);
    float u4 = f3(p[12], p[13], p[14]);
    s = fmaxf(f3(u0, u1, u2), f3(u3, u4, p[15])) + emit;
    sm[j] = s;
  }

  // asm operand setup (low-32 of a flat LDS pointer == LDS byte offset;
  // apertures are 4 GB aligned on AMDGCN — R6-validated on this hardware)
  uint32_t za = (uint32_t)(uintptr_t)sm;
  uint32_t wa = za + 4u * (uint32_t)j;
  uint32_t ta = (uint32_t)(uintptr_t)tl4 + 16u * (uint32_t)j;
  uint64_t em = (uint64_t)(uintptr_t)(pb + (size_t)4 * KS);  // row t=4
  uint64_t cpa = (uint64_t)(uintptr_t)(cpb + KS);            // checkpoint 1
  uint64_t fa = (uint64_t)(uintptr_t)(fin + (size_t)b * KS + j);

  asm volatile(
      // ---- prologue ----
      "s_waitcnt vmcnt(0) lgkmcnt(0)\n"
      "v_mov_b32 v176, %[sinit]\n"
      "v_mov_b32 v183, %[wa]\n"
      "v_mov_b32 v184, %[ta]\n"
      "v_mov_b32 v189, %[za]\n"
      "v_mov_b32 v192, %[emlo]\n"
      "v_mov_b32 v193, %[emhi]\n"
      "v_mov_b32 v194, %[cplo]\n"
      "v_mov_b32 v195, %[cphi]\n"
      "v_mov_b32 v196, %[fnlo]\n"
      "v_mov_b32 v197, %[fnhi]\n"
      // T column -> v[32:95] (resident for the whole loop)
      "ds_read_b128 v[32:35], v184 offset:0\n"
      "ds_read_b128 v[36:39], v184 offset:1024\n"
      "ds_read_b128 v[40:43], v184 offset:2048\n"
      "ds_read_b128 v[44:47], v184 offset:3072\n"
      "ds_read_b128 v[48:51], v184 offset:4096\n"
      "ds_read_b128 v[52:55], v184 offset:5120\n"
      "ds_read_b128 v[56:59], v184 offset:6144\n"
      "ds_read_b128 v[60:63], v184 offset:7168\n"
      "ds_read_b128 v[64:67], v184 offset:8192\n"
      "ds_read_b128 v[68:71], v184 offset:9216\n"
      "ds_read_b128 v[72:75], v184 offset:10240\n"
      "ds_read_b128 v[76:79], v184 offset:11264\n"
      "ds_read_b128 v[80:83], v184 offset:12288\n"
      "ds_read_b128 v[84:87], v184 offset:13312\n"
      "ds_read_b128 v[88:91], v184 offset:14336\n"
      "ds_read_b128 v[92:95], v184 offset:15360\n"
      // prime 4-deep emission ring: e0..e3 = rows t=4..7
      "global_load_dword v177, v[192:193], off offset:0\n"
      "global_load_dword v178, v[192:193], off offset:256\n"
      "global_load_dword v179, v[192:193], off offset:512\n"
      "global_load_dword v180, v[192:193], off offset:768\n"
      "s_waitcnt lgkmcnt(0)\n"
      "s_mov_b32 s20, 1023\n"
      // ---- main loop: 1023 groups x 4 steps ----
      "CRFLOOP%=:\n"
      // last group (s20==1): rewind emis base 4096 B so the 4 prefetch
      // loads stay in-bounds (their values are never consumed)
      "s_cmp_eq_u32 s20, 1\n"
      "s_cbranch_scc0 NOADJ%=\n"
      "v_add_co_u32 v192, vcc, 0xfffff000, v192\n"
      "v_addc_co_u32 v193, vcc, -1, v193, vcc\n"
      "NOADJ%=:\n"
      POS("v177", "1024", CPBLK)
      POS("v178", "1280", "")
      POS("v179", "1536", "")
      POS("v180", "1792", "")
      // advance emission base one group (4 rows = 1024 B)
      "v_add_co_u32 v192, vcc, 0x400, v192\n"
      "v_addc_co_u32 v193, vcc, 0, v193, vcc\n"
      "s_sub_u32 s20, s20, 1\n"
      "s_cmp_lg_u32 s20, 0\n"
      "s_cbranch_scc1 CRFLOOP%=\n"
      // ---- epilogue: final state ----
      "global_store_dword v[196:197], v176, off\n"
      "s_waitcnt vmcnt(0)\n"
      :
      : [sinit] "v"(s), [wa] "v"(wa), [ta] "v"(ta), [za] "v"(za),
        [emlo] "v"((uint32_t)em), [emhi] "v"((uint32_t)(em >> 32)),
        [cplo] "v"((uint32_t)cpa), [cphi] "v"((uint32_t)(cpa >> 32)),
        [fnlo] "v"((uint32_t)fa), [fnhi] "v"((uint32_t)(fa >> 32))
      : "memory", "vcc", "scc", "s20", "s21",
        "v32", "v33", "v34", "v35", "v36", "v37", "v38", "v39", "v40", "v41",
        "v42", "v43", "v44", "v45", "v46", "v47", "v48", "v49", "v50", "v51",
        "v52", "v53", "v54", "v55", "v56", "v57", "v58", "v59", "v60", "v61",
        "v62", "v63", "v64", "v65", "v66", "v67", "v68", "v69", "v70", "v71",
        "v72", "v73", "v74", "v75", "v76", "v77", "v78", "v79", "v80", "v81",
        "v82", "v83", "v84", "v85", "v86", "v87", "v88", "v89", "v90", "v91",
        "v92", "v93", "v94", "v95", "v96", "v97", "v98", "v99", "v100",
        "v101", "v102", "v103", "v104", "v105", "v106", "v107", "v108",
        "v109", "v110", "v111", "v112", "v113", "v114", "v115", "v116",
        "v117", "v118", "v119", "v120", "v121", "v122", "v123", "v124",
        "v125", "v126", "v127", "v128", "v129", "v130", "v131", "v132",
        "v133", "v134", "v135", "v136", "v137", "v138", "v139", "v140",
        "v141", "v142", "v143", "v144", "v145", "v146", "v147", "v148",
        "v149", "v150", "v151", "v152", "v153", "v154", "v155", "v156",
        "v157", "v158", "v159", "v160", "v161", "v162", "v163", "v164",
        "v165", "v166", "v167", "v168", "v169", "v170", "v171", "v172",
        "v173", "v174", "v175", "v176", "v177", "v178", "v179", "v180",
        "v181", "v182", "v183", "v184", "v185", "v186", "v187", "v188",
        "v189", "v190", "v191", "v192", "v193", "v194", "v195", "v196",
        "v197");
}

// ---------------------------------------------------------------------------
// Backpointer reconstruction (unchanged, best-measured rest-of-pipeline):
// per (batch, chunk) wave recomputes states from the checkpoint
// (bit-identical: fp32 max is exact, sums identical), derives bp[t][j],
// and fuses the speculative chunk-map chase via ds_bpermute.
// 8192 waves -> latency hidden by TLP.
// ---------------------------------------------------------------------------
__global__ __launch_bounds__(64) void crf_bp(
    const float* __restrict__ pot, const float* __restrict__ trans,
    const float* __restrict__ cp, unsigned char* __restrict__ bp,
    unsigned char* __restrict__ map) {
  const int b = blockIdx.x;
  const int ch = blockIdx.y;
  const int j = threadIdx.x;
  __shared__ float4 sm4[KS / 4];
  float* sm = (float*)sm4;

  float c[KS];
#pragma unroll
  for (int i = 0; i < KS; ++i) c[i] = trans[i * KS + j];

  float s = cp[((size_t)b * NCHUNK + ch) * KS + j];
  const int t0 = ch * 64;
  const int hi = min(t0 + 64, TLEN - 1);
  const float* pb = pot + (size_t)b * TLEN * KS + j;
  unsigned char* bpb = bp + (size_t)b * TLEN * KS + j;

  sm[j] = s;
  int tag = j;  // forward-composed backward map
  float emit = pb[(size_t)(t0 + 1) * KS];
  for (int t = t0 + 1; t <= hi; ++t) {
    float emit_next = pb[(size_t)min(t + 1, TLEN - 1) * KS];

    float m[KS];
#pragma unroll
    for (int q = 0; q < KS / 4; ++q) {
      float4 v = sm4[q];
      m[4 * q + 0] = v.x + c[4 * q + 0];
      m[4 * q + 1] = v.y + c[4 * q + 1];
      m[4 * q + 2] = v.z + c[4 * q + 2];
      m[4 * q + 3] = v.w + c[4 * q + 3];
    }
    float best = tree64(m);

    // first-occurrence argmax: descending exact-equality scan
    int bi = 63;
#pragma unroll
    for (int i = 62; i >= 0; --i) bi = (m[i] == best) ? i : bi;

    bpb[(size_t)t * KS] = (unsigned char)bi;
    s = best + emit;
    sm[j] = s;
    emit = emit_next;

    // g_t[k] = g_{t-1}[bp_t[k]]: lane k pulls lane bi_k's tag
    tag = __builtin_amdgcn_ds_bpermute(bi << 2, tag);
  }
  map[((size_t)b * NCHUNK + ch) * KS + j] = (unsigned char)tag;
}

// ---------------------------------------------------------------------------
// Compose chunk maps per batch (serial over 64 chunks, parallel over batches).
// Also does the final-state argmax (first-occurrence, strict >).
// ---------------------------------------------------------------------------
__global__ void crf_compose(const unsigned char* __restrict__ map,
                            const float* __restrict__ fin,
                            unsigned char* __restrict__ e,
                            int* __restrict__ tags_out) {
  const int b = blockIdx.x * blockDim.x + threadIdx.x;
  if (b >= BATCH) return;
  const float* fb = fin + (size_t)b * KS;
  float best = fb[0];
  int cur = 0;
  for (int i = 1; i < KS; ++i) {
    float v = fb[i];
    if (v > best) { best = v; cur = i; }
  }
  tags_out[(size_t)b * TLEN + (TLEN - 1)] = cur;
  for (int ch = NCHUNK - 1; ch >= 0; --ch) {
    e[(size_t)b * NCHUNK + ch] = (unsigned char)cur;
    cur = map[((size_t)b * NCHUNK + ch) * KS + cur];
  }
}

// ---------------------------------------------------------------------------
// Extract per-chunk paths from known entering tags (parallel over B*NCHUNK).
// ---------------------------------------------------------------------------
__global__ void crf_extract(const unsigned char* __restrict__ bp,
                            const unsigned char* __restrict__ e,
                            int* __restrict__ tags_out) {
  const int idx = blockIdx.x * blockDim.x + threadIdx.x;  // b*NCHUNK + c
  if (idx >= BATCH * NCHUNK) return;
  const int b = idx >> 6;
  const int c = idx & (NCHUNK - 1);
  const int lo = 64 * c + 1;
  const int hi = min(64 * c + 64, TLEN - 1);
  const unsigned char* bpb = bp + (size_t)b * TLEN * KS;
  int* to = tags_out + (size_t)b * TLEN;
  int tag = e[(size_t)b * NCHUNK + c];
  for (int t = hi; t >= lo; --t) {
    tag = bpb[(size_t)t * KS + tag];
    to[t - 1] = tag;
  }
}

// ---------------------------------------------------------------------------
// Sequence lengths = sum(mask) per batch.
// ---------------------------------------------------------------------------
__global__ __launch_bounds__(64) void crf_lens(const int* __restrict__ mask,
                                               int* __restrict__ out) {
  const int b = blockIdx.x;
  const int l = threadIdx.x;
  const int* mb = mask + (size_t)b * TLEN;
  int sum = 0;
  for (int t = l; t < TLEN; t += 64) sum += mb[t];
#pragma unroll
  for (int off = 32; off > 0; off >>= 1) sum += __shfl_down(sum, off, 64);
  if (l == 0) out[b] = sum;
}

extern "C" void kernel_launch(void* const* d_in, const int* in_sizes, int n_in,
                              void* d_out, int out_size, void* d_ws,
                              size_t ws_size, hipStream_t stream) {
  const float* pot = (const float*)d_in[0];    // (128, 4096, 64) fp32
  const float* trans = (const float*)d_in[1];  // (64, 64) fp32
  const int* mask = (const int*)d_in[2];       // (128, 4096) int32

  int* out = (int*)d_out;  // [tags: 128*4096][lens: 128]
  int* tags_out = out;
  int* lens_out = out + (size_t)BATCH * TLEN;

  // workspace layout
  char* w = (char*)d_ws;
  unsigned char* bp = (unsigned char*)w;                     // 33,554,432 B
  float* cp = (float*)(bp + (size_t)BATCH * TLEN * KS);      //  2,097,152 B
  float* fin = cp + (size_t)BATCH * NCHUNK * KS;             //     32,768 B
  unsigned char* map = (unsigned char*)(fin + (size_t)BATCH * KS);  // 524,288 B
  unsigned char* e = map + (size_t)BATCH * NCHUNK * KS;      //      8,192 B

  crf_fwd<<<BATCH, 64, 0, stream>>>(pot, trans, cp, fin);
  crf_lens<<<BATCH, 64, 0, stream>>>(mask, lens_out);
  crf_bp<<<dim3(BATCH, NCHUNK), 64, 0, stream>>>(pot, trans, cp, bp, map);
  crf_compose<<<1, BATCH, 0, stream>>>(map, fin, e, tags_out);
  crf_extract<<<(BATCH * NCHUNK + 255) / 256, 256, 0, stream>>>(bp, e, tags_out);
}